// Round 1
// baseline (796.923 us; speedup 1.0000x reference)
//
#include <hip/hip_runtime.h>
#include <hip/hip_bf16.h>

// out = inverse(M M^T + EPS*I) per pixel, M = x[b, :, :, h, w]^T  (16x64)
// x: [B=4, C=64, K=16, H=128, W=128] f32 ; out: [B,H,W,16,16] f32

#define K 16
#define C 64
#define HW 16384           // 128*128
#define EPSR 1e-6f

__device__ __forceinline__ constexpr int tidx(int i, int j) {  // i >= j
    return i * (i + 1) / 2 + j;
}

__global__ __launch_bounds__(256, 1)
void spectral_inv_kernel(const float* __restrict__ x, float* __restrict__ out) {
    const int p = blockIdx.x * blockDim.x + threadIdx.x;   // pixel id, 65536 total
    const int w = p & 127;
    const int h = (p >> 7) & 127;
    const int b = p >> 14;

    const float* xp = x + (size_t)b * (C * K * HW) + (size_t)h * 128 + w;

    float s[136];
    #pragma unroll
    for (int i = 0; i < 136; ++i) s[i] = 0.0f;

    // ---- Gram: s[i][j] = sum_c m[i]*m[j], lower triangle ----
    #pragma unroll 2
    for (int c = 0; c < C; ++c) {
        const float* xc = xp + (size_t)c * (K * HW);
        float m[K];
        #pragma unroll
        for (int k = 0; k < K; ++k) m[k] = xc[(size_t)k * HW];
        #pragma unroll
        for (int i = 0; i < K; ++i)
            #pragma unroll
            for (int j = 0; j <= i; ++j)
                s[tidx(i, j)] = fmaf(m[i], m[j], s[tidx(i, j)]);
    }

    // ---- regularize ----
    #pragma unroll
    for (int i = 0; i < K; ++i) s[tidx(i, i)] += EPSR;

    // ---- Cholesky in place: off-diag = L[i][j], diag = 1/L[j][j] ----
    #pragma unroll
    for (int j = 0; j < K; ++j) {
        float d = s[tidx(j, j)];
        #pragma unroll
        for (int q = 0; q < j; ++q) d = fmaf(-s[tidx(j, q)], s[tidx(j, q)], d);
        const float invd = 1.0f / sqrtf(d);
        s[tidx(j, j)] = invd;
        #pragma unroll
        for (int i = j + 1; i < K; ++i) {
            float v = s[tidx(i, j)];
            #pragma unroll
            for (int q = 0; q < j; ++q) v = fmaf(-s[tidx(i, q)], s[tidx(j, q)], v);
            s[tidx(i, j)] = v * invd;
        }
    }

    // ---- invert L in place (diag already inverted): M = L^{-1} ----
    // M[i][j] = -M[i][i] * ( L[i][j]*M[j][j] + sum_{q=j+1..i-1} L[i][q]*M[q][j] )
    #pragma unroll
    for (int j = 0; j < K; ++j) {
        #pragma unroll
        for (int i = j + 1; i < K; ++i) {
            float sum = s[tidx(i, j)] * s[tidx(j, j)];
            #pragma unroll
            for (int q = j + 1; q < i; ++q)
                sum = fmaf(s[tidx(i, q)], s[tidx(q, j)], sum);
            s[tidx(i, j)] = -s[tidx(i, i)] * sum;
        }
    }

    // ---- A^{-1} = M^T M in place (j asc, i asc): A[i][j] = sum_{q>=i} M[q][i]*M[q][j]
    #pragma unroll
    for (int j = 0; j < K; ++j) {
        #pragma unroll
        for (int i = j; i < K; ++i) {
            float sum = 0.0f;
            #pragma unroll
            for (int q = i; q < K; ++q)
                sum = fmaf(s[tidx(q, i)], s[tidx(q, j)], sum);
            s[tidx(i, j)] = sum;   // safe: reads use rows >= i, written rows < i only
        }
    }

    // ---- write full symmetric 16x16, float4 stores ----
    float* op = out + (size_t)p * (K * K);
    #pragma unroll
    for (int i = 0; i < K; ++i) {
        #pragma unroll
        for (int jq = 0; jq < K / 4; ++jq) {
            float4 v;
            {
                const int j0 = jq * 4;
                const float a0 = (i >= j0 + 0) ? s[tidx(i > j0 + 0 ? i : j0 + 0, i > j0 + 0 ? j0 + 0 : i)] : s[tidx(j0 + 0, i)];
                const float a1 = (i >= j0 + 1) ? s[tidx(i > j0 + 1 ? i : j0 + 1, i > j0 + 1 ? j0 + 1 : i)] : s[tidx(j0 + 1, i)];
                const float a2 = (i >= j0 + 2) ? s[tidx(i > j0 + 2 ? i : j0 + 2, i > j0 + 2 ? j0 + 2 : i)] : s[tidx(j0 + 2, i)];
                const float a3 = (i >= j0 + 3) ? s[tidx(i > j0 + 3 ? i : j0 + 3, i > j0 + 3 ? j0 + 3 : i)] : s[tidx(j0 + 3, i)];
                v.x = a0; v.y = a1; v.z = a2; v.w = a3;
            }
            *reinterpret_cast<float4*>(op + i * K + jq * 4) = v;
        }
    }
}

extern "C" void kernel_launch(void* const* d_in, const int* in_sizes, int n_in,
                              void* d_out, int out_size, void* d_ws, size_t ws_size,
                              hipStream_t stream) {
    const float* x = (const float*)d_in[0];
    float* out = (float*)d_out;
    // 4*128*128 = 65536 pixels, one thread each
    dim3 grid(65536 / 256), block(256);
    hipLaunchKernelGGL(spectral_inv_kernel, grid, block, 0, stream, x, out);
}

// Round 2
// 319.015 us; speedup vs baseline: 2.4981x; 2.4981x over previous
//
#include <hip/hip_runtime.h>
#include <hip/hip_bf16.h>
#include <utility>

// reference == inverse(M M^T + EPS*I) per pixel (V diag(1/l) V^T of SPD matrix)
// x: [B=4, C=64, K=16, H=128, W=128] f32 ; out: [B,H,W,16,16] f32
// Kernel A: Gram + EPS*I -> d_out (full symmetric 16x16 per pixel)
// Kernel B: in-place per-pixel Cholesky inversion of d_out

#define EPSR 1e-6f

__device__ __host__ constexpr int rowof(int t) {
    int i = 0;
    while ((i + 1) * (i + 2) / 2 <= t) ++i;
    return i;
}
__device__ __host__ constexpr int colof(int t) { return t - rowof(t) * (rowof(t) + 1) / 2; }

__device__ __forceinline__ constexpr int tidx(int i, int j) {  // i >= j
    return i * (i + 1) / 2 + j;
}

// ---------------- Kernel A: Gram ----------------

template<int P>
__device__ __forceinline__ void fma_pair(const float (&m)[16], float& a) {
    a = fmaf(m[rowof(P)], m[colof(P)], a);
}

template<int G, int... TT>
__device__ __forceinline__ void fma_group(const float (&m)[16], float (&acc)[34],
                                          std::integer_sequence<int, TT...>) {
    (fma_pair<G * 34 + TT>(m, acc[TT]), ...);
}

template<int G>
__device__ __forceinline__ void chunk_fma(const float* __restrict__ smem, int lane,
                                          float (&acc)[34]) {
    #pragma unroll
    for (int cc = 0; cc < 8; ++cc) {
        const float* sp = smem + cc * 1024 + lane;
        float m[16];
        #pragma unroll
        for (int k = 0; k < 16; ++k) m[k] = sp[k * 64];
        fma_group<G>(m, acc, std::make_integer_sequence<int, 34>{});
    }
}

template<int P>
__device__ __forceinline__ void store_pair(float* op, float v) {
    constexpr int i = rowof(P), j = colof(P);
    op[i * 16 + j] = (i == j) ? (v + EPSR) : v;
    if constexpr (i != j) op[j * 16 + i] = v;
}

template<int G, int... TT>
__device__ __forceinline__ void store_group(float* op, const float (&acc)[34],
                                            std::integer_sequence<int, TT...>) {
    (store_pair<G * 34 + TT>(op, acc[TT]), ...);
}

__global__ __launch_bounds__(256, 4)
void gram_kernel(const float* __restrict__ x, float* __restrict__ out) {
    const int tid = threadIdx.x;
    const int lane = tid & 63;
    const int wv = tid >> 6;
    const int p0 = blockIdx.x * 64;          // 64 consecutive pixels, same h row-half
    const int p = p0 + lane;
    const int b = p0 >> 14;
    const int hw0 = p0 & 16383;              // h*128 + w0, w0 in {0,64}

    const float* xb = x + (size_t)b * (64 * 16 * 16384) + hw0;

    __shared__ __align__(16) float smem[8 * 16 * 64];   // 32 KB: [cc][k][p]

    float acc[34];
    #pragma unroll
    for (int t = 0; t < 34; ++t) acc[t] = 0.0f;

    for (int c0 = 0; c0 < 64; c0 += 8) {
        __syncthreads();
        // stage 8 c's x 16 k's x 64 pixels, float4-coalesced
        #pragma unroll
        for (int q = 0; q < 8; ++q) {
            const int f = q * 256 + tid;         // float4 index 0..2047
            const int row = f >> 4;              // cc*16 + k
            const int cc = row >> 4;
            const int k = row & 15;
            const int p4 = (f & 15) << 2;
            const float4 v = *reinterpret_cast<const float4*>(
                xb + (size_t)(c0 + cc) * 262144 + (size_t)k * 16384 + p4);
            *reinterpret_cast<float4*>(&smem[f << 2]) = v;
        }
        __syncthreads();
        if      (wv == 0) chunk_fma<0>(smem, lane, acc);
        else if (wv == 1) chunk_fma<1>(smem, lane, acc);
        else if (wv == 2) chunk_fma<2>(smem, lane, acc);
        else              chunk_fma<3>(smem, lane, acc);
    }

    float* op = out + (size_t)p * 256;
    if      (wv == 0) store_group<0>(op, acc, std::make_integer_sequence<int, 34>{});
    else if (wv == 1) store_group<1>(op, acc, std::make_integer_sequence<int, 34>{});
    else if (wv == 2) store_group<2>(op, acc, std::make_integer_sequence<int, 34>{});
    else              store_group<3>(op, acc, std::make_integer_sequence<int, 34>{});
}

// ---------------- Kernel B: per-pixel SPD inverse (Cholesky) ----------------

__global__ __launch_bounds__(64, 1)
void inv_kernel(float* __restrict__ out) {
    const int p = blockIdx.x * 64 + threadIdx.x;
    float* op = out + (size_t)p * 256;

    float s[136];

    // load lower triangle (float4 row reads; dead lanes folded at compile time)
    #pragma unroll
    for (int i = 0; i < 16; ++i) {
        #pragma unroll
        for (int j4 = 0; j4 <= i / 4; ++j4) {
            const float4 v = *reinterpret_cast<const float4*>(op + i * 16 + j4 * 4);
            if (4 * j4 + 0 <= i) s[tidx(i, 4 * j4 + 0 <= i ? 4 * j4 + 0 : 0)] = v.x;
            if (4 * j4 + 1 <= i) s[tidx(i, 4 * j4 + 1 <= i ? 4 * j4 + 1 : 0)] = v.y;
            if (4 * j4 + 2 <= i) s[tidx(i, 4 * j4 + 2 <= i ? 4 * j4 + 2 : 0)] = v.z;
            if (4 * j4 + 3 <= i) s[tidx(i, 4 * j4 + 3 <= i ? 4 * j4 + 3 : 0)] = v.w;
        }
    }

    // Cholesky in place: off-diag = L[i][j], diag = 1/L[j][j]
    #pragma unroll
    for (int j = 0; j < 16; ++j) {
        float d = s[tidx(j, j)];
        #pragma unroll
        for (int q = 0; q < j; ++q) d = fmaf(-s[tidx(j, q)], s[tidx(j, q)], d);
        const float invd = 1.0f / sqrtf(d);
        s[tidx(j, j)] = invd;
        #pragma unroll
        for (int i = j + 1; i < 16; ++i) {
            float v = s[tidx(i, j)];
            #pragma unroll
            for (int q = 0; q < j; ++q) v = fmaf(-s[tidx(i, q)], s[tidx(j, q)], v);
            s[tidx(i, j)] = v * invd;
        }
    }

    // invert L in place (diag already inverted): M = L^{-1}
    #pragma unroll
    for (int j = 0; j < 16; ++j) {
        #pragma unroll
        for (int i = j + 1; i < 16; ++i) {
            float sum = s[tidx(i, j)] * s[tidx(j, j)];
            #pragma unroll
            for (int q = j + 1; q < i; ++q)
                sum = fmaf(s[tidx(i, q)], s[tidx(q, j)], sum);
            s[tidx(i, j)] = -s[tidx(i, i)] * sum;
        }
    }

    // A^{-1} = M^T M in place
    #pragma unroll
    for (int j = 0; j < 16; ++j) {
        #pragma unroll
        for (int i = j; i < 16; ++i) {
            float sum = 0.0f;
            #pragma unroll
            for (int q = i; q < 16; ++q)
                sum = fmaf(s[tidx(q, i)], s[tidx(q, j)], sum);
            s[tidx(i, j)] = sum;
        }
    }

    // write full symmetric 16x16, float4 stores
    #pragma unroll
    for (int i = 0; i < 16; ++i) {
        #pragma unroll
        for (int jq = 0; jq < 4; ++jq) {
            const int j0 = jq * 4;
            float4 v;
            v.x = (i >= j0 + 0) ? s[tidx(i, j0 + 0)] : s[tidx(j0 + 0, i)];
            v.y = (i >= j0 + 1) ? s[tidx(i > j0 + 1 ? i : j0 + 1, i > j0 + 1 ? j0 + 1 : i)] : s[tidx(j0 + 1, i)];
            v.z = (i >= j0 + 2) ? s[tidx(i > j0 + 2 ? i : j0 + 2, i > j0 + 2 ? j0 + 2 : i)] : s[tidx(j0 + 2, i)];
            v.w = (i >= j0 + 3) ? s[tidx(i > j0 + 3 ? i : j0 + 3, i > j0 + 3 ? j0 + 3 : i)] : s[tidx(j0 + 3, i)];
            *reinterpret_cast<float4*>(op + i * 16 + j0) = v;
        }
    }
}

extern "C" void kernel_launch(void* const* d_in, const int* in_sizes, int n_in,
                              void* d_out, int out_size, void* d_ws, size_t ws_size,
                              hipStream_t stream) {
    const float* x = (const float*)d_in[0];
    float* out = (float*)d_out;
    hipLaunchKernelGGL(gram_kernel, dim3(1024), dim3(256), 0, stream, x, out);
    hipLaunchKernelGGL(inv_kernel,  dim3(1024), dim3(64),  0, stream, out);
}